// Round 1
// baseline (886.315 us; speedup 1.0000x reference)
//
#include <hip/hip_runtime.h>
#include <limits.h>

// Problem constants (from reference): C classes, N slots, D dims, B batch.
#define CC 1000
#define NN 256
#define DD 512
#define BB 4096
#define D4 (DD / 4)   // 128 float4 per row

// ---------------------------------------------------------------------------
// Kernel 1: init last_pos[c] = -1 (workspace is re-poisoned to 0xAA each call)
// ---------------------------------------------------------------------------
__global__ void init_lastpos(int* last_pos) {
    int c = blockIdx.x * blockDim.x + threadIdx.x;
    if (c < CC) last_pos[c] = -1;
}

// ---------------------------------------------------------------------------
// Kernel 2: per batch element b, t = argmax(batch_targets[b,:]) with
// first-occurrence tie-break (jnp.argmax semantics); if selected and
// conf > confidences[t, N-1], atomicMax(&last_pos[t], b)  == segment_max of
// last valid position per class.
// ---------------------------------------------------------------------------
__global__ void __launch_bounds__(256) push_kernel(
        const int* __restrict__ targets_mat,   // [B, C]
        const float* __restrict__ bconf,       // [B]
        const int* __restrict__ smask,         // [B]
        const float* __restrict__ conf,        // [C, N]
        int* __restrict__ last_pos) {          // [C]
    int b = blockIdx.x;
    int tid = threadIdx.x;
    const int* row = targets_mat + (size_t)b * CC;
    int bestv = INT_MIN, besti = 0;
    for (int i = tid; i < CC; i += 256) {
        int v = row[i];
        // strictly-greater keeps first occurrence within a thread's rising i
        if (v > bestv) { bestv = v; besti = i; }
    }
    __shared__ int sv[256], si[256];
    sv[tid] = bestv; si[tid] = besti;
    __syncthreads();
    for (int off = 128; off > 0; off >>= 1) {
        if (tid < off) {
            int v2 = sv[tid + off], i2 = si[tid + off];
            if (v2 > sv[tid] || (v2 == sv[tid] && i2 < si[tid])) {
                sv[tid] = v2; si[tid] = i2;
            }
        }
        __syncthreads();
    }
    if (tid == 0) {
        int t = si[0];
        bool valid = (smask[b] != 0) && (bconf[b] > conf[(size_t)t * NN + (NN - 1)]);
        if (valid) atomicMax(&last_pos[t], b);
    }
}

// ---------------------------------------------------------------------------
// Kernel 3: per class, build the post-push confidence row, compute the stable
// descending rank of every slot (composite key: conf desc, idx asc — exactly
// jnp.argsort(-conf) stable), and emit src[c][pos] = source memory row for
// output position pos.  Negative value -(1+lp) encodes "batch_features[lp]".
// One 256-thread block per class; O(N^2)=65536 LDS-broadcast compares.
// ---------------------------------------------------------------------------
__global__ void __launch_bounds__(256) sort_kernel(
        const float* __restrict__ conf,        // [C, N]
        const float* __restrict__ bconf,       // [B]
        const int* __restrict__ last_pos,      // [C]
        int* __restrict__ src) {               // [C, N]
    int c = blockIdx.x;
    int tid = threadIdx.x;                     // slot index o = tid
    __shared__ float skey[NN];
    __shared__ int ssrc[NN];
    int lp = last_pos[c];
    bool updated = (lp >= 0);
    float key;
    if (tid == NN - 1)
        key = updated ? bconf[lp] : conf[(size_t)c * NN + (NN - 1)];
    else
        key = conf[(size_t)c * NN + tid];
    skey[tid] = key;
    __syncthreads();
    int rank = 0;
    for (int k = 0; k < NN; ++k) {
        float other = skey[k];                 // broadcast read, no bank conflict
        rank += (other > key || (other == key && k < tid)) ? 1 : 0;
    }
    // source row in original memory for this slot (after the shift-push)
    int s;
    if (updated) s = (tid == NN - 1) ? (-1 - lp) : (tid + 1);
    else         s = tid;
    ssrc[rank] = s;                            // ranks are a permutation
    __syncthreads();
    src[(size_t)c * NN + tid] = ssrc[tid];
}

// ---------------------------------------------------------------------------
// Kernel 4: gather — out[c, pos, :] = (s>=0) ? memory[c, s, :]
//                                            : batch_features[-1-s, :]
// float4 coalesced; grid (C, 4), 64 rows/block, 2 rows per 256-thread pass.
// ---------------------------------------------------------------------------
__global__ void __launch_bounds__(256) gather_kernel(
        const float4* __restrict__ mem4,       // [C*N*D4]
        const float4* __restrict__ feat4,      // [B*D4]
        const int* __restrict__ src,           // [C, N]
        float4* __restrict__ out4) {           // [C*N*D4]
    int c = blockIdx.x;
    int rowbase = blockIdx.y * 64;
    int tid = threadIdx.x;
    int lane_row = tid >> 7;                   // 0 or 1
    int col = tid & 127;                       // float4 column
    for (int r = 0; r < 64; r += 2) {
        int j = rowbase + r + lane_row;
        int s = src[(size_t)c * NN + j];
        const float4* sp = (s >= 0)
            ? (mem4 + ((size_t)c * NN + s) * D4)
            : (feat4 + (size_t)(-1 - s) * D4);
        out4[((size_t)c * NN + j) * D4 + col] = sp[col];
    }
}

extern "C" void kernel_launch(void* const* d_in, const int* in_sizes, int n_in,
                              void* d_out, int out_size, void* d_ws, size_t ws_size,
                              hipStream_t stream) {
    const float* batch_features = (const float*)d_in[0];   // [B, D]
    const int*   batch_targets  = (const int*)d_in[1];     // [B, C]
    const float* batch_conf     = (const float*)d_in[2];   // [B]
    const int*   selected_mask  = (const int*)d_in[3];     // [B]
    const float* memory         = (const float*)d_in[4];   // [C, N, D]
    const float* confidences    = (const float*)d_in[5];   // [C, N]
    float* out = (float*)d_out;

    int* last_pos = (int*)d_ws;                // C ints
    int* src      = last_pos + CC;             // C*N ints

    init_lastpos<<<(CC + 255) / 256, 256, 0, stream>>>(last_pos);
    push_kernel<<<BB, 256, 0, stream>>>(batch_targets, batch_conf,
                                        selected_mask, confidences, last_pos);
    sort_kernel<<<CC, 256, 0, stream>>>(confidences, batch_conf, last_pos, src);
    gather_kernel<<<dim3(CC, 4), 256, 0, stream>>>(
        (const float4*)memory, (const float4*)batch_features, src, (float4*)out);
}